// Round 10
// baseline (207.625 us; speedup 1.0000x reference)
//
#include <hip/hip_runtime.h>
#include <math.h>

#define NB 16
#define DIN 512
#define TT 4096
#define DCB 8
#define KC 1024
#define NW 8            // waves per block

// ws layout (floats):
// [0,4096)      w_inT[d][c]
// [4096,8192)   w_out[o][c]
// [8192,9216)   cb2[k]
// [9216,10240)  per-block commit partials (1024)
// scratch for ablation variants (guarded by ws_size):
// [4M)   idx scratch, [5M) commit scratch, [8M) out scratch (134 MB)

__global__ __launch_bounds__(512) void vq_setup(
    const float* __restrict__ in_v, const float* __restrict__ in_g,
    const float* __restrict__ out_v, const float* __restrict__ out_g,
    const float* __restrict__ cb, float* __restrict__ ws)
{
    int tid = threadIdx.x;
    float* w_inT = ws;
    float* w_out = ws + 4096;
    float* cb2   = ws + 8192;

    {   // w_in: 8 rows of 512; one wave per row
        int c    = tid >> 6;
        int lane = tid & 63;
        const float* v = in_v + c * DIN;
        float s = 0.f;
        #pragma unroll
        for (int i = 0; i < DIN; i += 64) {
            float x = v[i + lane];
            s += x * x;
        }
        #pragma unroll
        for (int off = 32; off > 0; off >>= 1) s += __shfl_xor(s, off, 64);
        float sq = sqrtf(s);
        float g  = in_g[c];
        #pragma unroll
        for (int i = 0; i < DIN; i += 64) {
            int d = i + lane;
            w_inT[d * DCB + c] = (g * v[d]) / sq;
        }
    }
    {   // w_out: 512 rows of 8
        int o = tid;
        const float* v = out_v + o * DCB;
        float s = 0.f;
        #pragma unroll
        for (int c = 0; c < DCB; ++c) s += v[c] * v[c];
        float sq = sqrtf(s);
        float g  = out_g[o];
        #pragma unroll
        for (int c = 0; c < DCB; ++c) w_out[o * DCB + c] = (g * v[c]) / sq;
    }
    for (int k = tid; k < KC; k += 512) {
        const float* r = cb + k * DCB;
        float s = 0.f;
        #pragma unroll
        for (int c = 0; c < DCB; ++c) s += r[c] * r[c];
        cb2[k] = s;
    }
}

// V: 0=full  1=no-outproj  2=no-scan  3=no-inproj
template<int V>
__global__ __launch_bounds__(512, 4) void vq_main_t(
    const float* __restrict__ z, const float* __restrict__ in_b,
    const float* __restrict__ out_b, const float* __restrict__ cb,
    const float* __restrict__ ws, float* __restrict__ commit_dst,
    float* __restrict__ idx_dst, float* __restrict__ out_dst)
{
    constexpr bool IN   = (V != 3);
    constexpr bool SCAN = (V != 2);
    constexpr bool OUT  = (V != 1);

    __shared__ float s_buf[KC * DCB];    // 32 KB overlay: red then cb
    __shared__ float s_sd[NW][64];
    __shared__ int   s_si[NW][64];

    const float* w_inT = ws;
    const float* w_out = ws + 4096;
    const float* cb2w  = ws + 8192;

    int tid  = threadIdx.x;
    int w    = tid >> 6;
    int wu   = __builtin_amdgcn_readfirstlane(w);
    int lane = tid & 63;
    int blk  = blockIdx.x;               // 0..1023
    int b    = blk >> 6;
    int t    = (blk & 63) * 64 + lane;

    float ze[DCB];

    if constexpr (IN) {
        const float* zp = z + (size_t)b * DIN * TT + t;
        #pragma unroll
        for (int c = 0; c < DCB; ++c) ze[c] = 0.f;
        int d0 = wu * 64;
        #pragma unroll 8
        for (int dd = 0; dd < 64; ++dd) {
            int d = d0 + dd;
            float zv = zp[(size_t)d * TT];       // coalesced
            const float* wi = w_inT + d * DCB;   // uniform -> s_load
            #pragma unroll
            for (int c = 0; c < DCB; ++c) ze[c] = fmaf(wi[c], zv, ze[c]);
        }
        float* redw = s_buf + w * (DCB * 64);
        #pragma unroll
        for (int c = 0; c < DCB; ++c) redw[c * 64 + lane] = ze[c];
    } else {
        // synthesized ze (no z reads); varies with t so scan work is real
        #pragma unroll
        for (int c = 0; c < DCB; ++c)
            ze[c] = in_b[c] + 1e-4f * (float)((t + 3 * c) & 63);
        if (tid == 0) { s_sd[0][0] = 0.f; s_si[0][0] = 0; }  // keep LDS size
    }

    float4 p0, p1, p2, p3;
    if constexpr (SCAN) {
        p0 = ((const float4*)cb)[tid];
        p1 = ((const float4*)cb)[512 + tid];
        p2 = ((const float4*)cb)[1024 + tid];
        p3 = ((const float4*)cb)[1536 + tid];
    }

    if constexpr (IN) {
        __syncthreads();   // (1) red visible
        #pragma unroll
        for (int c = 0; c < DCB; ++c) {
            float s = 0.f;
            #pragma unroll
            for (int w2 = 0; w2 < NW; ++w2) s += s_buf[w2 * (DCB * 64) + c * 64 + lane];
            ze[c] = s + in_b[c];
        }
        __syncthreads();   // (2) red dead
    }

    int   gbi;
    float4 qa, qb;

    if constexpr (SCAN) {
        ((float4*)s_buf)[tid]        = p0;
        ((float4*)s_buf)[512 + tid]  = p1;
        ((float4*)s_buf)[1024 + tid] = p2;
        ((float4*)s_buf)[1536 + tid] = p3;
        __syncthreads();   // (3) cb visible

        float enc2 = 0.f;
        #pragma unroll
        for (int c = 0; c < DCB; ++c) enc2 += ze[c] * ze[c];

        float best = 3.4e38f;
        int   bi   = 0;
        int   k0   = wu * 128;
        #pragma unroll 4
        for (int kk = 0; kk < 128; ++kk) {
            int k = k0 + kk;
            float4 r0 = ((const float4*)s_buf)[2 * k];
            float4 r1 = ((const float4*)s_buf)[2 * k + 1];
            float dot = fmaf(ze[0], r0.x, fmaf(ze[1], r0.y, fmaf(ze[2], r0.z, fmaf(ze[3], r0.w,
                        fmaf(ze[4], r1.x, fmaf(ze[5], r1.y, fmaf(ze[6], r1.z, ze[7] * r1.w)))))));
            float dk  = (enc2 - 2.0f * dot) + cb2w[k];
            if (dk < best) { best = dk; bi = k; }
        }
        s_sd[w][lane] = best;
        s_si[w][lane] = bi;
        __syncthreads();   // (4)

        float gbest = s_sd[0][lane];
        gbi = s_si[0][lane];
        #pragma unroll
        for (int w2 = 1; w2 < NW; ++w2) {
            float d2 = s_sd[w2][lane];
            int   i2 = s_si[w2][lane];
            if (d2 < gbest) { gbest = d2; gbi = i2; }
        }
        qa = ((const float4*)s_buf)[2 * gbi];
        qb = ((const float4*)s_buf)[2 * gbi + 1];
    } else {
        gbi = (lane * 16 + wu + blk * 13) & (KC - 1);   // fake, deterministic
        const float* cq = cb + (size_t)gbi * DCB;
        qa = *(const float4*)cq;
        qb = *(const float4*)(cq + 4);
        if (tid == 0) s_buf[blk & 8191] = 0.f;          // keep LDS size
    }

    // ---- commit loss + indices: wave 0 only (keeps ze+q live in ALL variants) ----
    if (wu == 0) {
        float cl = 0.f, f;
        f = ze[0]-qa.x; cl = fmaf(f,f,cl);
        f = ze[1]-qa.y; cl = fmaf(f,f,cl);
        f = ze[2]-qa.z; cl = fmaf(f,f,cl);
        f = ze[3]-qa.w; cl = fmaf(f,f,cl);
        f = ze[4]-qb.x; cl = fmaf(f,f,cl);
        f = ze[5]-qb.y; cl = fmaf(f,f,cl);
        f = ze[6]-qb.z; cl = fmaf(f,f,cl);
        f = ze[7]-qb.w; cl = fmaf(f,f,cl);
        #pragma unroll
        for (int off = 32; off > 0; off >>= 1) cl += __shfl_xor(cl, off, 64);
        if (lane == 0) commit_dst[blk] = cl;
        idx_dst[(size_t)b * TT + t] = (float)gbi;
    }

    if constexpr (OUT) {
        float* outp = out_dst + (size_t)b * DIN * TT + t;
        int o0 = wu * 64;
        #pragma unroll 4
        for (int oo = 0; oo < 64; ++oo) {
            int o = o0 + oo;
            const float* wo = w_out + o * DCB;   // uniform -> s_load
            float obias = out_b[o];
            float a = fmaf(wo[0], qa.x, fmaf(wo[1], qa.y, fmaf(wo[2], qa.z, fmaf(wo[3], qa.w,
                      fmaf(wo[4], qb.x, fmaf(wo[5], qb.y, fmaf(wo[6], qb.z, wo[7] * qb.w)))))));
            outp[(size_t)o * TT] = a + obias;
        }
    } else {
        // keep q formally used beyond commit (wave0 already uses it; waves 1-7:)
        asm volatile("" :: "v"(qa.x), "v"(qb.w));
    }
}

__global__ __launch_bounds__(64) void vq_commit(
    const float* __restrict__ ws_commit, float* __restrict__ out)
{
    int b    = blockIdx.x;
    int lane = threadIdx.x;
    float s = ws_commit[b * 64 + lane];
    #pragma unroll
    for (int off = 32; off > 0; off >>= 1) s += __shfl_xor(s, off, 64);
    if (lane == 0)
        out[(size_t)NB * DIN * TT + b] = s * (1.0f / (DCB * TT));
}

extern "C" void kernel_launch(void* const* d_in, const int* in_sizes, int n_in,
                              void* d_out, int out_size, void* d_ws, size_t ws_size,
                              hipStream_t stream) {
    const float* z     = (const float*)d_in[0];
    const float* in_v  = (const float*)d_in[1];
    const float* in_g  = (const float*)d_in[2];
    const float* in_b  = (const float*)d_in[3];
    const float* out_v = (const float*)d_in[4];
    const float* out_g = (const float*)d_in[5];
    const float* out_b = (const float*)d_in[6];
    const float* cb    = (const float*)d_in[7];

    float* ws  = (float*)d_ws;
    float* out = (float*)d_out;

    vq_setup<<<1, 512, 0, stream>>>(in_v, in_g, out_v, out_g, cb, ws);

    // V0: the real kernel (writes d_out)
    vq_main_t<0><<<1024, 512, 0, stream>>>(z, in_b, out_b, cb, ws,
        ws + 9216, out + (size_t)NB * DIN * TT + NB, out);
    vq_commit<<<NB, 64, 0, stream>>>(ws + 9216, out);

    // Ablation variants -> ws scratch only (diagnostic round; inflates dur_us)
    if (ws_size >= 200ull * 1024 * 1024) {
        float* idx_s = ws + (4u << 20);
        float* cm_s  = ws + (5u << 20);
        float* out_s = ws + (8u << 20);
        vq_main_t<1><<<1024, 512, 0, stream>>>(z, in_b, out_b, cb, ws, cm_s, idx_s, out_s);
        vq_main_t<2><<<1024, 512, 0, stream>>>(z, in_b, out_b, cb, ws, cm_s, idx_s, out_s);
        vq_main_t<3><<<1024, 512, 0, stream>>>(z, in_b, out_b, cb, ws, cm_s, idx_s, out_s);
    }
}

// Round 11
// 76.661 us; speedup vs baseline: 2.7084x; 2.7084x over previous
//
#include <hip/hip_runtime.h>
#include <math.h>

#define NB 16
#define DIN 512
#define TT 4096
#define DCB 8
#define KC 1024
#define NW 8            // waves per block

// ws layout (floats):
// [0,4096)      w_inT[d][c]
// [4096,8192)   w_out[o][c]
// [8192,9216)   cb2[k]
// [9216,10240)  per-block commit partials (1024 = 16 b x 64)

__global__ __launch_bounds__(512) void vq_setup(
    const float* __restrict__ in_v, const float* __restrict__ in_g,
    const float* __restrict__ out_v, const float* __restrict__ out_g,
    const float* __restrict__ cb, float* __restrict__ ws)
{
    int tid = threadIdx.x;
    float* w_inT = ws;
    float* w_out = ws + 4096;
    float* cb2   = ws + 8192;

    {   // w_in: 8 rows of 512; one wave per row
        int c    = tid >> 6;
        int lane = tid & 63;
        const float* v = in_v + c * DIN;
        float s = 0.f;
        #pragma unroll
        for (int i = 0; i < DIN; i += 64) {
            float x = v[i + lane];
            s += x * x;
        }
        #pragma unroll
        for (int off = 32; off > 0; off >>= 1) s += __shfl_xor(s, off, 64);
        float sq = sqrtf(s);
        float g  = in_g[c];
        #pragma unroll
        for (int i = 0; i < DIN; i += 64) {
            int d = i + lane;
            w_inT[d * DCB + c] = (g * v[d]) / sq;
        }
    }
    {   // w_out: 512 rows of 8
        int o = tid;
        const float* v = out_v + o * DCB;
        float s = 0.f;
        #pragma unroll
        for (int c = 0; c < DCB; ++c) s += v[c] * v[c];
        float sq = sqrtf(s);
        float g  = out_g[o];
        #pragma unroll
        for (int c = 0; c < DCB; ++c) w_out[o * DCB + c] = (g * v[c]) / sq;
    }
    for (int k = tid; k < KC; k += 512) {
        const float* r = cb + k * DCB;
        float s = 0.f;
        #pragma unroll
        for (int c = 0; c < DCB; ++c) s += r[c] * r[c];
        cb2[k] = s;
    }
}

// Pipelined fused kernel. 512 blocks x 512 threads.
// block = (b, pair p); chunk A = t [128p,128p+64), chunk B = [128p+64,128p+128).
// wave w owns d/k/o slices as before. Pipeline: inA | scanA | (inB ∥ outA) |
// scanB | outB  -> chunk-B reads overlap chunk-A writes.
__global__ __launch_bounds__(512, 4) void vq_main(
    const float* __restrict__ z, const float* __restrict__ in_b,
    const float* __restrict__ out_b, const float* __restrict__ cb,
    const float* __restrict__ ws, float* __restrict__ ws_commit,
    float* __restrict__ out)
{
    __shared__ float s_cb[KC * DCB];     // 32 KB, persistent
    __shared__ float s_redA[NW * DCB * 64];  // 16 KB
    __shared__ float s_redB[NW * DCB * 64];  // 16 KB
    __shared__ float s_sdA[NW][64];
    __shared__ int   s_siA[NW][64];
    __shared__ float s_sdB[NW][64];
    __shared__ int   s_siB[NW][64];      // total 72 KB -> 2 blocks/CU

    const float* w_inT = ws;
    const float* w_out = ws + 4096;
    const float* cb2w  = ws + 8192;

    int tid  = threadIdx.x;
    int w    = tid >> 6;
    int wu   = __builtin_amdgcn_readfirstlane(w);
    int lane = tid & 63;
    int blk  = blockIdx.x;               // 0..511
    int b    = blk >> 5;
    int p    = blk & 31;
    int tA   = p * 128 + lane;

    // ---- stage cb into its own LDS region (short live range) ----
    {
        float4 c0 = ((const float4*)cb)[tid];
        float4 c1 = ((const float4*)cb)[512 + tid];
        float4 c2 = ((const float4*)cb)[1024 + tid];
        float4 c3 = ((const float4*)cb)[1536 + tid];
        ((float4*)s_cb)[tid]        = c0;
        ((float4*)s_cb)[512 + tid]  = c1;
        ((float4*)s_cb)[1024 + tid] = c2;
        ((float4*)s_cb)[1536 + tid] = c3;
    }

    const float* zpA = z + (size_t)b * DIN * TT + tA;
    int d0 = wu * 64;

    // ---- in-proj A: 64 d-loads, MLP-batched 8 ----
    float zeA[DCB];
    #pragma unroll
    for (int c = 0; c < DCB; ++c) zeA[c] = 0.f;
    for (int db = 0; db < 64; db += 8) {
        float v[8];
        #pragma unroll
        for (int j = 0; j < 8; ++j) v[j] = zpA[(size_t)(d0 + db + j) * TT];
        #pragma unroll
        for (int j = 0; j < 8; ++j) {
            const float* wi = w_inT + (d0 + db + j) * DCB;   // uniform -> s_load
            #pragma unroll
            for (int c = 0; c < DCB; ++c) zeA[c] = fmaf(wi[c], v[j], zeA[c]);
        }
    }
    {
        float* redw = s_redA + w * (DCB * 64);
        #pragma unroll
        for (int c = 0; c < DCB; ++c) redw[c * 64 + lane] = zeA[c];
    }
    __syncthreads();   // (1) redA + s_cb visible

    // ---- reduce A ----
    #pragma unroll
    for (int c = 0; c < DCB; ++c) {
        float s = 0.f;
        #pragma unroll
        for (int w2 = 0; w2 < NW; ++w2) s += s_redA[w2 * (DCB * 64) + c * 64 + lane];
        zeA[c] = s + in_b[c];
    }

    // ---- scan A over k in [wu*128, ...) ----
    float enc2 = 0.f;
    #pragma unroll
    for (int c = 0; c < DCB; ++c) enc2 += zeA[c] * zeA[c];
    {
        float best = 3.4e38f;
        int   bi   = 0;
        int   k0   = wu * 128;
        #pragma unroll 4
        for (int kk = 0; kk < 128; ++kk) {
            int k = k0 + kk;
            float4 r0 = ((const float4*)s_cb)[2 * k];
            float4 r1 = ((const float4*)s_cb)[2 * k + 1];
            float dot = fmaf(zeA[0], r0.x, fmaf(zeA[1], r0.y, fmaf(zeA[2], r0.z, fmaf(zeA[3], r0.w,
                        fmaf(zeA[4], r1.x, fmaf(zeA[5], r1.y, fmaf(zeA[6], r1.z, zeA[7] * r1.w)))))));
            float dk  = (enc2 - 2.0f * dot) + cb2w[k];
            if (dk < best) { best = dk; bi = k; }
        }
        s_sdA[w][lane] = best;
        s_siA[w][lane] = bi;
    }
    __syncthreads();   // (2) sdA/siA visible

    float gbest = s_sdA[0][lane];
    int   gbiA  = s_siA[0][lane];
    #pragma unroll
    for (int w2 = 1; w2 < NW; ++w2) {
        float d2 = s_sdA[w2][lane];
        int   i2 = s_siA[w2][lane];
        if (d2 < gbest) { gbest = d2; gbiA = i2; }
    }
    float4 qAa = ((const float4*)s_cb)[2 * gbiA];
    float4 qAb = ((const float4*)s_cb)[2 * gbiA + 1];

    // ---- commit + idx for A (wave 0 only) ----
    if (wu == 0) {
        float cl = 0.f, f;
        f = zeA[0]-qAa.x; cl = fmaf(f,f,cl);
        f = zeA[1]-qAa.y; cl = fmaf(f,f,cl);
        f = zeA[2]-qAa.z; cl = fmaf(f,f,cl);
        f = zeA[3]-qAa.w; cl = fmaf(f,f,cl);
        f = zeA[4]-qAb.x; cl = fmaf(f,f,cl);
        f = zeA[5]-qAb.y; cl = fmaf(f,f,cl);
        f = zeA[6]-qAb.z; cl = fmaf(f,f,cl);
        f = zeA[7]-qAb.w; cl = fmaf(f,f,cl);
        #pragma unroll
        for (int off = 32; off > 0; off >>= 1) cl += __shfl_xor(cl, off, 64);
        if (lane == 0) ws_commit[b * 64 + 2 * p] = cl;
        out[(size_t)NB * DIN * TT + NB + (size_t)b * TT + tA] = (float)gbiA;
    }

    // ---- pipeline core: in-proj B loads ∥ out-proj A stores ----
    const float* zpB  = zpA + 64;
    float* outpA = out + (size_t)b * DIN * TT + tA;
    float zeB[DCB];
    #pragma unroll
    for (int c = 0; c < DCB; ++c) zeB[c] = 0.f;
    for (int i = 0; i < 64; i += 4) {
        float v[4];
        #pragma unroll
        for (int j = 0; j < 4; ++j) v[j] = zpB[(size_t)(d0 + i + j) * TT];  // reads
        #pragma unroll
        for (int j = 0; j < 4; ++j) {                                       // writes
            int o = d0 + i + j;
            const float* wo = w_out + o * DCB;   // uniform -> s_load
            float a = fmaf(wo[0], qAa.x, fmaf(wo[1], qAa.y, fmaf(wo[2], qAa.z, fmaf(wo[3], qAa.w,
                      fmaf(wo[4], qAb.x, fmaf(wo[5], qAb.y, fmaf(wo[6], qAb.z, wo[7] * qAb.w)))))));
            outpA[(size_t)o * TT] = a + out_b[o];
        }
        #pragma unroll
        for (int j = 0; j < 4; ++j) {
            const float* wi = w_inT + (d0 + i + j) * DCB;
            #pragma unroll
            for (int c = 0; c < DCB; ++c) zeB[c] = fmaf(wi[c], v[j], zeB[c]);
        }
    }
    {
        float* redw = s_redB + w * (DCB * 64);
        #pragma unroll
        for (int c = 0; c < DCB; ++c) redw[c * 64 + lane] = zeB[c];
    }
    __syncthreads();   // (3) redB visible

    // ---- reduce B ----
    #pragma unroll
    for (int c = 0; c < DCB; ++c) {
        float s = 0.f;
        #pragma unroll
        for (int w2 = 0; w2 < NW; ++w2) s += s_redB[w2 * (DCB * 64) + c * 64 + lane];
        zeB[c] = s + in_b[c];
    }

    // ---- scan B ----
    float enc2b = 0.f;
    #pragma unroll
    for (int c = 0; c < DCB; ++c) enc2b += zeB[c] * zeB[c];
    {
        float best = 3.4e38f;
        int   bi   = 0;
        int   k0   = wu * 128;
        #pragma unroll 4
        for (int kk = 0; kk < 128; ++kk) {
            int k = k0 + kk;
            float4 r0 = ((const float4*)s_cb)[2 * k];
            float4 r1 = ((const float4*)s_cb)[2 * k + 1];
            float dot = fmaf(zeB[0], r0.x, fmaf(zeB[1], r0.y, fmaf(zeB[2], r0.z, fmaf(zeB[3], r0.w,
                        fmaf(zeB[4], r1.x, fmaf(zeB[5], r1.y, fmaf(zeB[6], r1.z, zeB[7] * r1.w)))))));
            float dk  = (enc2b - 2.0f * dot) + cb2w[k];
            if (dk < best) { best = dk; bi = k; }
        }
        s_sdB[w][lane] = best;
        s_siB[w][lane] = bi;
    }
    __syncthreads();   // (4) sdB/siB visible

    float gbestB = s_sdB[0][lane];
    int   gbiB   = s_siB[0][lane];
    #pragma unroll
    for (int w2 = 1; w2 < NW; ++w2) {
        float d2 = s_sdB[w2][lane];
        int   i2 = s_siB[w2][lane];
        if (d2 < gbestB) { gbestB = d2; gbiB = i2; }
    }
    float4 qBa = ((const float4*)s_cb)[2 * gbiB];
    float4 qBb = ((const float4*)s_cb)[2 * gbiB + 1];

    // ---- commit + idx for B (wave 0 only) ----
    if (wu == 0) {
        float cl = 0.f, f;
        f = zeB[0]-qBa.x; cl = fmaf(f,f,cl);
        f = zeB[1]-qBa.y; cl = fmaf(f,f,cl);
        f = zeB[2]-qBa.z; cl = fmaf(f,f,cl);
        f = zeB[3]-qBa.w; cl = fmaf(f,f,cl);
        f = zeB[4]-qBb.x; cl = fmaf(f,f,cl);
        f = zeB[5]-qBb.y; cl = fmaf(f,f,cl);
        f = zeB[6]-qBb.z; cl = fmaf(f,f,cl);
        f = zeB[7]-qBb.w; cl = fmaf(f,f,cl);
        #pragma unroll
        for (int off = 32; off > 0; off >>= 1) cl += __shfl_xor(cl, off, 64);
        if (lane == 0) ws_commit[b * 64 + 2 * p + 1] = cl;
        out[(size_t)NB * DIN * TT + NB + (size_t)b * TT + tA + 64] = (float)gbiB;
    }

    // ---- out-proj B ----
    float* outpB = outpA + 64;
    #pragma unroll 4
    for (int oo = 0; oo < 64; ++oo) {
        int o = d0 + oo;
        const float* wo = w_out + o * DCB;   // uniform -> s_load
        float a = fmaf(wo[0], qBa.x, fmaf(wo[1], qBa.y, fmaf(wo[2], qBa.z, fmaf(wo[3], qBa.w,
                  fmaf(wo[4], qBb.x, fmaf(wo[5], qBb.y, fmaf(wo[6], qBb.z, wo[7] * qBb.w)))))));
        outpB[(size_t)o * TT] = a + out_b[o];
    }
}

__global__ __launch_bounds__(64) void vq_commit(
    const float* __restrict__ ws_commit, float* __restrict__ out)
{
    int b    = blockIdx.x;
    int lane = threadIdx.x;
    float s = ws_commit[b * 64 + lane];
    #pragma unroll
    for (int off = 32; off > 0; off >>= 1) s += __shfl_xor(s, off, 64);
    if (lane == 0)
        out[(size_t)NB * DIN * TT + b] = s * (1.0f / (DCB * TT));
}

extern "C" void kernel_launch(void* const* d_in, const int* in_sizes, int n_in,
                              void* d_out, int out_size, void* d_ws, size_t ws_size,
                              hipStream_t stream) {
    const float* z     = (const float*)d_in[0];
    const float* in_v  = (const float*)d_in[1];
    const float* in_g  = (const float*)d_in[2];
    const float* in_b  = (const float*)d_in[3];
    const float* out_v = (const float*)d_in[4];
    const float* out_g = (const float*)d_in[5];
    const float* out_b = (const float*)d_in[6];
    const float* cb    = (const float*)d_in[7];

    float* ws  = (float*)d_ws;
    float* out = (float*)d_out;

    vq_setup<<<1, 512, 0, stream>>>(in_v, in_g, out_v, out_g, cb, ws);
    vq_main<<<512, 512, 0, stream>>>(z, in_b, out_b, cb, ws, ws + 9216, out);
    vq_commit<<<NB, 64, 0, stream>>>(ws + 9216, out);
}

// Round 12
// 70.534 us; speedup vs baseline: 2.9436x; 1.0869x over previous
//
#include <hip/hip_runtime.h>
#include <math.h>

#define NB 16
#define DIN 512
#define TT 4096
#define DCB 8
#define KC 1024
#define NW 8            // waves per block
#define TC 128          // t-chunk per block (2 per lane, float2)

// ws layout (floats):
// [0,4096)      w_inT[d][c]   (transposed)
// [4096,8192)   w_out[o][c]
// [8192,9216)   cb2[k]
// [9216,9728)   per-block commit partials (512)

__global__ __launch_bounds__(512) void vq_setup(
    const float* __restrict__ in_v, const float* __restrict__ in_g,
    const float* __restrict__ out_v, const float* __restrict__ out_g,
    const float* __restrict__ cb, float* __restrict__ ws)
{
    int tid = threadIdx.x;
    float* w_inT = ws;
    float* w_out = ws + 4096;
    float* cb2   = ws + 8192;

    {   // w_in: 8 rows of 512; one wave per row
        int c    = tid >> 6;
        int lane = tid & 63;
        const float* v = in_v + c * DIN;
        float s = 0.f;
        #pragma unroll
        for (int i = 0; i < DIN; i += 64) {
            float x = v[i + lane];
            s += x * x;
        }
        #pragma unroll
        for (int off = 32; off > 0; off >>= 1) s += __shfl_xor(s, off, 64);
        float sq = sqrtf(s);
        float g  = in_g[c];
        #pragma unroll
        for (int i = 0; i < DIN; i += 64) {
            int d = i + lane;
            w_inT[d * DCB + c] = (g * v[d]) / sq;
        }
    }
    {   // w_out: 512 rows of 8
        int o = tid;
        const float* v = out_v + o * DCB;
        float s = 0.f;
        #pragma unroll
        for (int c = 0; c < DCB; ++c) s += v[c] * v[c];
        float sq = sqrtf(s);
        float g  = out_g[o];
        #pragma unroll
        for (int c = 0; c < DCB; ++c) w_out[o * DCB + c] = (g * v[c]) / sq;
    }
    for (int k = tid; k < KC; k += 512) {
        const float* r = cb + k * DCB;
        float s = 0.f;
        #pragma unroll
        for (int c = 0; c < DCB; ++c) s += r[c] * r[c];
        cb2[k] = s;
    }
}

// Fused main kernel — r8 base + 8-deep load batching in the in-projection.
// 512 blocks x 512 threads; block = (b, 128-t chunk).
// wave w owns d in [64w,64w+64), k in [128w,128w+128), o in [64w,64w+64).
__global__ __launch_bounds__(512, 4) void vq_main(
    const float* __restrict__ z, const float* __restrict__ in_b,
    const float* __restrict__ out_b, const float* __restrict__ cb,
    const float* __restrict__ ws, float* __restrict__ ws_commit,
    float* __restrict__ out)
{
    __shared__ float s_cb[KC * DCB];        // 32 KB  [k][c]
    __shared__ float s_cb2[KC];             // 4 KB
    __shared__ float s_red[NW * DCB * TC];  // 32 KB
    __shared__ float s_sd[NW][TC];          // 4 KB
    __shared__ int   s_si[NW][TC];          // 4 KB

    const float* w_inT = ws;
    const float* w_out = ws + 4096;

    int tid  = threadIdx.x;
    int w    = tid >> 6;
    int wu   = __builtin_amdgcn_readfirstlane(w);
    int lane = tid & 63;
    int blk  = blockIdx.x;               // 0..511
    int b    = blk >> 5;
    int t0   = (blk & 31) * TC;
    int tl   = 2 * lane;

    // ---- stage cb + cb2 into LDS immediately (short live range) ----
    {
        float4 c0 = ((const float4*)cb)[tid];
        float4 c1 = ((const float4*)cb)[512 + tid];
        float4 c2 = ((const float4*)cb)[1024 + tid];
        float4 c3 = ((const float4*)cb)[1536 + tid];
        ((float4*)s_cb)[tid]        = c0;
        ((float4*)s_cb)[512 + tid]  = c1;
        ((float4*)s_cb)[1024 + tid] = c2;
        ((float4*)s_cb)[1536 + tid] = c3;
        if (tid < 256) {
            float4 q = ((const float4*)(ws + 8192))[tid];
            ((float4*)s_cb2)[tid] = q;
        }
    }

    const float* zp = z + (size_t)b * DIN * TT + t0 + tl;

    // ---- in-projection over d in [wu*64, wu*64+64), 8-deep load batches ----
    float ze0[DCB], ze1[DCB];
    #pragma unroll
    for (int c = 0; c < DCB; ++c) { ze0[c] = 0.f; ze1[c] = 0.f; }

    int d0 = wu * 64;
    for (int db = 0; db < 64; db += 8) {
        float2 v[8];
        #pragma unroll
        for (int j = 0; j < 8; ++j)
            v[j] = *(const float2*)(zp + (size_t)(d0 + db + j) * TT);  // 8 loads in flight
        #pragma unroll
        for (int j = 0; j < 8; ++j) {
            const float* wi = w_inT + (d0 + db + j) * DCB;  // uniform -> s_load
            #pragma unroll
            for (int c = 0; c < DCB; ++c) {
                ze0[c] = fmaf(wi[c], v[j].x, ze0[c]);
                ze1[c] = fmaf(wi[c], v[j].y, ze1[c]);
            }
        }
    }

    // ---- write red partials ----
    float* redw = s_red + w * DCB * TC;
    #pragma unroll
    for (int c = 0; c < DCB; ++c) {
        redw[c * TC + tl]     = ze0[c];
        redw[c * TC + tl + 1] = ze1[c];
    }
    __syncthreads();   // (1) red + staged cb/cb2 visible

    // ---- cross-wave reduce of ze ----
    #pragma unroll
    for (int c = 0; c < DCB; ++c) {
        float s0 = 0.f, s1 = 0.f;
        #pragma unroll
        for (int w2 = 0; w2 < NW; ++w2) {
            s0 += s_red[(w2 * DCB + c) * TC + tl];
            s1 += s_red[(w2 * DCB + c) * TC + tl + 1];
        }
        ze0[c] = s0 + in_b[c];
        ze1[c] = s1 + in_b[c];
    }

    float enc20 = 0.f, enc21 = 0.f;
    #pragma unroll
    for (int c = 0; c < DCB; ++c) {
        enc20 += ze0[c] * ze0[c];
        enc21 += ze1[c] * ze1[c];
    }

    // ---- codebook partial argmin over k in [wu*128, wu*128+128), LDS reads ----
    float best0 = 3.4e38f, best1 = 3.4e38f;
    int   bi0   = 0,       bi1   = 0;
    int   k0    = wu * 128;
    #pragma unroll 4
    for (int kk = 0; kk < 128; ++kk) {
        int k = k0 + kk;
        float4 r0 = ((const float4*)s_cb)[2 * k];       // uniform -> broadcast
        float4 r1 = ((const float4*)s_cb)[2 * k + 1];
        float dot0 = fmaf(ze0[0], r0.x, fmaf(ze0[1], r0.y, fmaf(ze0[2], r0.z, fmaf(ze0[3], r0.w,
                     fmaf(ze0[4], r1.x, fmaf(ze0[5], r1.y, fmaf(ze0[6], r1.z, ze0[7] * r1.w)))))));
        float dot1 = fmaf(ze1[0], r0.x, fmaf(ze1[1], r0.y, fmaf(ze1[2], r0.z, fmaf(ze1[3], r0.w,
                     fmaf(ze1[4], r1.x, fmaf(ze1[5], r1.y, fmaf(ze1[6], r1.z, ze1[7] * r1.w)))))));
        float c2  = s_cb2[k];
        float dk0 = (enc20 - 2.0f * dot0) + c2;
        float dk1 = (enc21 - 2.0f * dot1) + c2;
        if (dk0 < best0) { best0 = dk0; bi0 = k; }
        if (dk1 < best1) { best1 = dk1; bi1 = k; }
    }
    s_sd[w][tl]     = best0;  s_si[w][tl]     = bi0;
    s_sd[w][tl + 1] = best1;  s_si[w][tl + 1] = bi1;
    __syncthreads();   // (2) sd/si visible

    // ---- ordered combine (w'=0..7, strict < keeps first min over k) ----
    float g0 = s_sd[0][tl], g1 = s_sd[0][tl + 1];
    int  gi0 = s_si[0][tl], gi1 = s_si[0][tl + 1];
    #pragma unroll
    for (int w2 = 1; w2 < NW; ++w2) {
        float d0_ = s_sd[w2][tl],     d1_ = s_sd[w2][tl + 1];
        int   i0_ = s_si[w2][tl],     i1_ = s_si[w2][tl + 1];
        if (d0_ < g0) { g0 = d0_; gi0 = i0_; }
        if (d1_ < g1) { g1 = d1_; gi1 = i1_; }
    }

    // ---- z_q rows from LDS ----
    float4 q0a = ((const float4*)s_cb)[2 * gi0], q0b = ((const float4*)s_cb)[2 * gi0 + 1];
    float4 q1a = ((const float4*)s_cb)[2 * gi1], q1b = ((const float4*)s_cb)[2 * gi1 + 1];

    // ---- commit loss + indices: wave 0 ONLY ----
    if (wu == 0) {
        float cl = 0.f;
        float f;
        f = ze0[0]-q0a.x; cl = fmaf(f,f,cl);  f = ze1[0]-q1a.x; cl = fmaf(f,f,cl);
        f = ze0[1]-q0a.y; cl = fmaf(f,f,cl);  f = ze1[1]-q1a.y; cl = fmaf(f,f,cl);
        f = ze0[2]-q0a.z; cl = fmaf(f,f,cl);  f = ze1[2]-q1a.z; cl = fmaf(f,f,cl);
        f = ze0[3]-q0a.w; cl = fmaf(f,f,cl);  f = ze1[3]-q1a.w; cl = fmaf(f,f,cl);
        f = ze0[4]-q0b.x; cl = fmaf(f,f,cl);  f = ze1[4]-q1b.x; cl = fmaf(f,f,cl);
        f = ze0[5]-q0b.y; cl = fmaf(f,f,cl);  f = ze1[5]-q1b.y; cl = fmaf(f,f,cl);
        f = ze0[6]-q0b.z; cl = fmaf(f,f,cl);  f = ze1[6]-q1b.z; cl = fmaf(f,f,cl);
        f = ze0[7]-q0b.w; cl = fmaf(f,f,cl);  f = ze1[7]-q1b.w; cl = fmaf(f,f,cl);
        #pragma unroll
        for (int off = 32; off > 0; off >>= 1) cl += __shfl_xor(cl, off, 64);
        if (lane == 0) ws_commit[blk] = cl;
        // indices (as float; whole out buffer is read as fp32)
        float2 iv = make_float2((float)gi0, (float)gi1);
        *(float2*)(out + (size_t)NB * DIN * TT + NB + (size_t)b * TT + t0 + tl) = iv;
    }

    // ---- out-projection over o in [wu*64, wu*64+64), s_load weights ----
    float* outp = out + (size_t)b * DIN * TT + t0 + tl;
    int o0 = wu * 64;
    #pragma unroll 4
    for (int oo = 0; oo < 64; ++oo) {
        int o = o0 + oo;
        const float* wo = w_out + o * DCB;   // uniform -> s_load_dwordx8
        float obias = out_b[o];              // uniform -> s_load
        float a0 = fmaf(wo[0], q0a.x, fmaf(wo[1], q0a.y, fmaf(wo[2], q0a.z, fmaf(wo[3], q0a.w,
                   fmaf(wo[4], q0b.x, fmaf(wo[5], q0b.y, fmaf(wo[6], q0b.z, wo[7] * q0b.w)))))));
        float a1 = fmaf(wo[0], q1a.x, fmaf(wo[1], q1a.y, fmaf(wo[2], q1a.z, fmaf(wo[3], q1a.w,
                   fmaf(wo[4], q1b.x, fmaf(wo[5], q1b.y, fmaf(wo[6], q1b.z, wo[7] * q1b.w)))))));
        *(float2*)(outp + (size_t)o * TT) = make_float2(a0 + obias, a1 + obias);
    }
}

__global__ __launch_bounds__(64) void vq_commit(
    const float* __restrict__ ws_commit, float* __restrict__ out)
{
    int b    = blockIdx.x;
    int lane = threadIdx.x;
    float s = (lane < 32) ? ws_commit[b * 32 + lane] : 0.f;
    #pragma unroll
    for (int off = 32; off > 0; off >>= 1) s += __shfl_xor(s, off, 64);
    if (lane == 0)
        out[(size_t)NB * DIN * TT + b] = s * (1.0f / (DCB * TT));
}

extern "C" void kernel_launch(void* const* d_in, const int* in_sizes, int n_in,
                              void* d_out, int out_size, void* d_ws, size_t ws_size,
                              hipStream_t stream) {
    const float* z     = (const float*)d_in[0];
    const float* in_v  = (const float*)d_in[1];
    const float* in_g  = (const float*)d_in[2];
    const float* in_b  = (const float*)d_in[3];
    const float* out_v = (const float*)d_in[4];
    const float* out_g = (const float*)d_in[5];
    const float* out_b = (const float*)d_in[6];
    const float* cb    = (const float*)d_in[7];

    float* ws  = (float*)d_ws;
    float* out = (float*)d_out;

    vq_setup<<<1, 512, 0, stream>>>(in_v, in_g, out_v, out_g, cb, ws);
    vq_main<<<512, 512, 0, stream>>>(z, in_b, out_b, cb, ws, ws + 9216, out);
    vq_commit<<<NB, 64, 0, stream>>>(ws + 9216, out);
}

// Round 13
// 67.457 us; speedup vs baseline: 3.0779x; 1.0456x over previous
//
#include <hip/hip_runtime.h>
#include <math.h>

#define NB 16
#define DIN 512
#define TT 4096
#define DCB 8
#define KC 1024
#define NW 8            // waves per block
#define TC 128          // t-chunk per block

// ws layout (floats):
// [0,4096)      w_inT[d][c]   (transposed)
// [4096,8192)   w_out[o][c]
// [8192,9216)   cb2[k]
// [9216,9728)   per-block commit partials (512)

__global__ __launch_bounds__(512) void vq_setup(
    const float* __restrict__ in_v, const float* __restrict__ in_g,
    const float* __restrict__ out_v, const float* __restrict__ out_g,
    const float* __restrict__ cb, float* __restrict__ ws)
{
    int tid = threadIdx.x;
    float* w_inT = ws;
    float* w_out = ws + 4096;
    float* cb2   = ws + 8192;

    {   // w_in: 8 rows of 512; one wave per row
        int c    = tid >> 6;
        int lane = tid & 63;
        const float* v = in_v + c * DIN;
        float s = 0.f;
        #pragma unroll
        for (int i = 0; i < DIN; i += 64) {
            float x = v[i + lane];
            s += x * x;
        }
        #pragma unroll
        for (int off = 32; off > 0; off >>= 1) s += __shfl_xor(s, off, 64);
        float sq = sqrtf(s);
        float g  = in_g[c];
        #pragma unroll
        for (int i = 0; i < DIN; i += 64) {
            int d = i + lane;
            w_inT[d * DCB + c] = (g * v[d]) / sq;
        }
    }
    {   // w_out: 512 rows of 8
        int o = tid;
        const float* v = out_v + o * DCB;
        float s = 0.f;
        #pragma unroll
        for (int c = 0; c < DCB; ++c) s += v[c] * v[c];
        float sq = sqrtf(s);
        float g  = out_g[o];
        #pragma unroll
        for (int c = 0; c < DCB; ++c) w_out[o * DCB + c] = (g * v[c]) / sq;
    }
    for (int k = tid; k < KC; k += 512) {
        const float* r = cb + k * DCB;
        float s = 0.f;
        #pragma unroll
        for (int c = 0; c < DCB; ++c) s += r[c] * r[c];
        cb2[k] = s;
    }
}

// Fused main. 512 blocks x 512 threads; block = (b, 128-t chunk).
// in-proj: wave w owns d in [64w,64w+64) (r12 verbatim).
// reduce: DISTRIBUTED — thread (w,lane) reduces (c=w, t=2lane..2lane+1) only.
// scan: lane handles 4 t's; k-slice = 64 k's at slice index s=2w+(lane>>5).
// tail (combine/commit/idx/out-proj): r12 verbatim.
__global__ __launch_bounds__(512, 4) void vq_main(
    const float* __restrict__ z, const float* __restrict__ in_b,
    const float* __restrict__ out_b, const float* __restrict__ cb,
    const float* __restrict__ ws, float* __restrict__ ws_commit,
    float* __restrict__ out)
{
    __shared__ float s_buf[KC * DCB];   // 32 KB overlay: red [w][c][t] -> cb [k][c]
    __shared__ float s_ze[DCB * TC];    // 4 KB  [c][t] reduced ze
    __shared__ float s_cb2[KC];         // 4 KB
    __shared__ float s_sd[16][TC];      // 8 KB
    __shared__ int   s_si[16][TC];      // 8 KB   total 56 KB

    const float* w_inT = ws;
    const float* w_out = ws + 4096;

    int tid  = threadIdx.x;
    int w    = tid >> 6;
    int wu   = __builtin_amdgcn_readfirstlane(w);
    int lane = tid & 63;
    int blk  = blockIdx.x;               // 0..511
    int b    = blk >> 5;
    int t0   = (blk & 31) * TC;
    int tl   = 2 * lane;

    // cb2 -> LDS at top (separate buffer, no alias)
    if (tid < 256) {
        float4 q = ((const float4*)(ws + 8192))[tid];
        ((float4*)s_cb2)[tid] = q;
    }

    const float* zp = z + (size_t)b * DIN * TT + t0 + tl;

    // ---- in-projection over d in [wu*64, wu*64+64) (r12 verbatim) ----
    float ze0[DCB], ze1[DCB];
    #pragma unroll
    for (int c = 0; c < DCB; ++c) { ze0[c] = 0.f; ze1[c] = 0.f; }

    int d0 = wu * 64;
    for (int db = 0; db < 64; db += 8) {
        float2 v[8];
        #pragma unroll
        for (int j = 0; j < 8; ++j)
            v[j] = *(const float2*)(zp + (size_t)(d0 + db + j) * TT);
        #pragma unroll
        for (int j = 0; j < 8; ++j) {
            const float* wi = w_inT + (d0 + db + j) * DCB;  // uniform -> s_load
            #pragma unroll
            for (int c = 0; c < DCB; ++c) {
                ze0[c] = fmaf(wi[c], v[j].x, ze0[c]);
                ze1[c] = fmaf(wi[c], v[j].y, ze1[c]);
            }
        }
    }

    // ---- write red partials [w][c][t] ----
    {
        float* redw = s_buf + w * (DCB * TC);
        #pragma unroll
        for (int c = 0; c < DCB; ++c)
            *(float2*)(redw + c * TC + tl) = make_float2(ze0[c], ze1[c]);
    }

    // ---- prefetch cb into regs (returns during reduce) ----
    float4 p0 = ((const float4*)cb)[tid];
    float4 p1 = ((const float4*)cb)[512 + tid];
    float4 p2 = ((const float4*)cb)[1024 + tid];
    float4 p3 = ((const float4*)cb)[1536 + tid];

    __syncthreads();   // (1) red visible

    // ---- distributed reduce: this thread owns (c=w, t=tl..tl+1) ----
    {
        float sa = 0.f, sb = 0.f;
        #pragma unroll
        for (int w2 = 0; w2 < NW; ++w2) {
            float2 r = *(const float2*)(s_buf + w2 * (DCB * TC) + w * TC + tl);
            sa += r.x; sb += r.y;
        }
        float bias = in_b[w];              // uniform -> s_load
        *(float2*)(s_ze + w * TC + tl) = make_float2(sa + bias, sb + bias);
    }
    __syncthreads();   // (2) red reads done, s_ze written -> s_buf reusable

    // ---- overwrite s_buf with codebook ----
    ((float4*)s_buf)[tid]        = p0;
    ((float4*)s_buf)[512 + tid]  = p1;
    ((float4*)s_buf)[1024 + tid] = p2;
    ((float4*)s_buf)[1536 + tid] = p3;
    __syncthreads();   // (3) cb + s_ze visible

    // ---- scan: lane -> 4 t's, 64-k slice ----
    {
        int h  = lane >> 5;
        int t4 = 4 * (lane & 31);
        int s  = 2 * w + h;                // slice index, k ascending with s
        int k0 = 64 * s;

        float zr[DCB][4];
        #pragma unroll
        for (int c = 0; c < DCB; ++c) {
            float4 v = *(const float4*)(s_ze + c * TC + t4);
            zr[c][0] = v.x; zr[c][1] = v.y; zr[c][2] = v.z; zr[c][3] = v.w;
        }
        float enc2[4];
        #pragma unroll
        for (int j = 0; j < 4; ++j) {
            float e = 0.f;
            #pragma unroll
            for (int c = 0; c < DCB; ++c) e += zr[c][j] * zr[c][j];
            enc2[j] = e;
        }

        float best[4] = {3.4e38f, 3.4e38f, 3.4e38f, 3.4e38f};
        int   bi[4]   = {0, 0, 0, 0};
        #pragma unroll 4
        for (int kk = 0; kk < 64; ++kk) {
            int k = k0 + kk;
            float4 r0 = ((const float4*)s_buf)[2 * k];
            float4 r1 = ((const float4*)s_buf)[2 * k + 1];
            float c2  = s_cb2[k];
            #pragma unroll
            for (int j = 0; j < 4; ++j) {
                float dot = fmaf(zr[0][j], r0.x, fmaf(zr[1][j], r0.y, fmaf(zr[2][j], r0.z, fmaf(zr[3][j], r0.w,
                            fmaf(zr[4][j], r1.x, fmaf(zr[5][j], r1.y, fmaf(zr[6][j], r1.z, zr[7][j] * r1.w)))))));
                float dk  = (enc2[j] - 2.0f * dot) + c2;
                if (dk < best[j]) { best[j] = dk; bi[j] = k; }
            }
        }
        *(float4*)(&s_sd[s][t4]) = make_float4(best[0], best[1], best[2], best[3]);
        *(int4*)  (&s_si[s][t4]) = make_int4(bi[0], bi[1], bi[2], bi[3]);
    }
    __syncthreads();   // (4) sd/si visible

    // ---- ordered combine over 16 slices (strict <, k-ascending) ----
    float g0 = s_sd[0][tl], g1 = s_sd[0][tl + 1];
    int  gi0 = s_si[0][tl], gi1 = s_si[0][tl + 1];
    #pragma unroll
    for (int s2 = 1; s2 < 16; ++s2) {
        float d0_ = s_sd[s2][tl],  d1_ = s_sd[s2][tl + 1];
        int   i0_ = s_si[s2][tl],  i1_ = s_si[s2][tl + 1];
        if (d0_ < g0) { g0 = d0_; gi0 = i0_; }
        if (d1_ < g1) { g1 = d1_; gi1 = i1_; }
    }

    // ---- z_q rows from LDS (per-lane divergent, as r12) ----
    float4 q0a = ((const float4*)s_buf)[2 * gi0], q0b = ((const float4*)s_buf)[2 * gi0 + 1];
    float4 q1a = ((const float4*)s_buf)[2 * gi1], q1b = ((const float4*)s_buf)[2 * gi1 + 1];

    // ---- commit loss + indices: wave 0 ONLY ----
    if (wu == 0) {
        float zeA[DCB], zeB[DCB];
        #pragma unroll
        for (int c = 0; c < DCB; ++c) {
            float2 zz = *(const float2*)(s_ze + c * TC + tl);
            zeA[c] = zz.x; zeB[c] = zz.y;
        }
        float cl = 0.f, f;
        f = zeA[0]-q0a.x; cl = fmaf(f,f,cl);  f = zeB[0]-q1a.x; cl = fmaf(f,f,cl);
        f = zeA[1]-q0a.y; cl = fmaf(f,f,cl);  f = zeB[1]-q1a.y; cl = fmaf(f,f,cl);
        f = zeA[2]-q0a.z; cl = fmaf(f,f,cl);  f = zeB[2]-q1a.z; cl = fmaf(f,f,cl);
        f = zeA[3]-q0a.w; cl = fmaf(f,f,cl);  f = zeB[3]-q1a.w; cl = fmaf(f,f,cl);
        f = zeA[4]-q0b.x; cl = fmaf(f,f,cl);  f = zeB[4]-q1b.x; cl = fmaf(f,f,cl);
        f = zeA[5]-q0b.y; cl = fmaf(f,f,cl);  f = zeB[5]-q1b.y; cl = fmaf(f,f,cl);
        f = zeA[6]-q0b.z; cl = fmaf(f,f,cl);  f = zeB[6]-q1b.z; cl = fmaf(f,f,cl);
        f = zeA[7]-q0b.w; cl = fmaf(f,f,cl);  f = zeB[7]-q1b.w; cl = fmaf(f,f,cl);
        #pragma unroll
        for (int off = 32; off > 0; off >>= 1) cl += __shfl_xor(cl, off, 64);
        if (lane == 0) ws_commit[blk] = cl;
        float2 iv = make_float2((float)gi0, (float)gi1);
        *(float2*)(out + (size_t)NB * DIN * TT + NB + (size_t)b * TT + t0 + tl) = iv;
    }

    // ---- out-projection over o in [wu*64, wu*64+64) (r12 verbatim) ----
    float* outp = out + (size_t)b * DIN * TT + t0 + tl;
    int o0 = wu * 64;
    #pragma unroll 4
    for (int oo = 0; oo < 64; ++oo) {
        int o = o0 + oo;
        const float* wo = w_out + o * DCB;   // uniform -> s_load_dwordx8
        float obias = out_b[o];              // uniform -> s_load
        float a0 = fmaf(wo[0], q0a.x, fmaf(wo[1], q0a.y, fmaf(wo[2], q0a.z, fmaf(wo[3], q0a.w,
                   fmaf(wo[4], q0b.x, fmaf(wo[5], q0b.y, fmaf(wo[6], q0b.z, wo[7] * q0b.w)))))));
        float a1 = fmaf(wo[0], q1a.x, fmaf(wo[1], q1a.y, fmaf(wo[2], q1a.z, fmaf(wo[3], q1a.w,
                   fmaf(wo[4], q1b.x, fmaf(wo[5], q1b.y, fmaf(wo[6], q1b.z, wo[7] * q1b.w)))))));
        *(float2*)(outp + (size_t)o * TT) = make_float2(a0 + obias, a1 + obias);
    }
}

__global__ __launch_bounds__(64) void vq_commit(
    const float* __restrict__ ws_commit, float* __restrict__ out)
{
    int b    = blockIdx.x;
    int lane = threadIdx.x;
    float s = (lane < 32) ? ws_commit[b * 32 + lane] : 0.f;
    #pragma unroll
    for (int off = 32; off > 0; off >>= 1) s += __shfl_xor(s, off, 64);
    if (lane == 0)
        out[(size_t)NB * DIN * TT + b] = s * (1.0f / (DCB * TT));
}

extern "C" void kernel_launch(void* const* d_in, const int* in_sizes, int n_in,
                              void* d_out, int out_size, void* d_ws, size_t ws_size,
                              hipStream_t stream) {
    const float* z     = (const float*)d_in[0];
    const float* in_v  = (const float*)d_in[1];
    const float* in_g  = (const float*)d_in[2];
    const float* in_b  = (const float*)d_in[3];
    const float* out_v = (const float*)d_in[4];
    const float* out_g = (const float*)d_in[5];
    const float* out_b = (const float*)d_in[6];
    const float* cb    = (const float*)d_in[7];

    float* ws  = (float*)d_ws;
    float* out = (float*)d_out;

    vq_setup<<<1, 512, 0, stream>>>(in_v, in_g, out_v, out_g, cb, ws);
    vq_main<<<512, 512, 0, stream>>>(z, in_b, out_b, cb, ws, ws + 9216, out);
    vq_commit<<<NB, 64, 0, stream>>>(ws + 9216, out);
}

// Round 14
// 66.298 us; speedup vs baseline: 3.1317x; 1.0175x over previous
//
#include <hip/hip_runtime.h>
#include <math.h>

#define NB 16
#define DIN 512
#define TT 4096
#define DCB 8
#define KC 1024
#define NW 8            // waves per block
#define TC 128          // t-chunk per block

typedef float v2f __attribute__((ext_vector_type(2)));

// v_pk_*_f32 with op_sel word-broadcast of src1 (wave-uniform cb operand).
// _LO: both result halves use src1.lo ; _HI: both use src1.hi.
#define PK_MUL_LO(d, a, b)    asm("v_pk_mul_f32 %0, %1, %2 op_sel_hi:[1,0]"       : "=v"(d) : "v"(a), "v"(b))
#define PK_MUL_HI(d, a, b)    asm("v_pk_mul_f32 %0, %1, %2 op_sel:[0,1]"          : "=v"(d) : "v"(a), "v"(b))
#define PK_FMA_LO(d, a, b, c) asm("v_pk_fma_f32 %0, %1, %2, %3 op_sel_hi:[1,0,1]" : "=v"(d) : "v"(a), "v"(b), "v"(c))
#define PK_FMA_HI(d, a, b, c) asm("v_pk_fma_f32 %0, %1, %2, %3 op_sel:[0,1,0]"    : "=v"(d) : "v"(a), "v"(b), "v"(c))
#define PK_FMA(d, a, b, c)    asm("v_pk_fma_f32 %0, %1, %2, %3"                   : "=v"(d) : "v"(a), "v"(b), "v"(c))
#define PK_ADD_LO(d, a, b)    asm("v_pk_add_f32 %0, %1, %2 op_sel_hi:[1,0]"       : "=v"(d) : "v"(a), "v"(b))
#define PK_ADD_HI(d, a, b)    asm("v_pk_add_f32 %0, %1, %2 op_sel:[0,1]"          : "=v"(d) : "v"(a), "v"(b))

// ws layout (floats):
// [0,4096)      w_inT[d][c]   (transposed)
// [4096,8192)   w_out[o][c]
// [8192,9216)   cb2[k]
// [9216,9728)   per-block commit partials (512)

__global__ __launch_bounds__(512) void vq_setup(
    const float* __restrict__ in_v, const float* __restrict__ in_g,
    const float* __restrict__ out_v, const float* __restrict__ out_g,
    const float* __restrict__ cb, float* __restrict__ ws)
{
    int tid = threadIdx.x;
    float* w_inT = ws;
    float* w_out = ws + 4096;
    float* cb2   = ws + 8192;

    {   // w_in: 8 rows of 512; one wave per row
        int c    = tid >> 6;
        int lane = tid & 63;
        const float* v = in_v + c * DIN;
        float s = 0.f;
        #pragma unroll
        for (int i = 0; i < DIN; i += 64) {
            float x = v[i + lane];
            s += x * x;
        }
        #pragma unroll
        for (int off = 32; off > 0; off >>= 1) s += __shfl_xor(s, off, 64);
        float sq = sqrtf(s);
        float g  = in_g[c];
        #pragma unroll
        for (int i = 0; i < DIN; i += 64) {
            int d = i + lane;
            w_inT[d * DCB + c] = (g * v[d]) / sq;
        }
    }
    {   // w_out: 512 rows of 8
        int o = tid;
        const float* v = out_v + o * DCB;
        float s = 0.f;
        #pragma unroll
        for (int c = 0; c < DCB; ++c) s += v[c] * v[c];
        float sq = sqrtf(s);
        float g  = out_g[o];
        #pragma unroll
        for (int c = 0; c < DCB; ++c) w_out[o * DCB + c] = (g * v[c]) / sq;
    }
    for (int k = tid; k < KC; k += 512) {
        const float* r = cb + k * DCB;
        float s = 0.f;
        #pragma unroll
        for (int c = 0; c < DCB; ++c) s += r[c] * r[c];
        cb2[k] = s;
    }
}

// Fused main (r13 structure; scan uses packed fp32 with bit-identical order).
__global__ __launch_bounds__(512, 4) void vq_main(
    const float* __restrict__ z, const float* __restrict__ in_b,
    const float* __restrict__ out_b, const float* __restrict__ cb,
    const float* __restrict__ ws, float* __restrict__ ws_commit,
    float* __restrict__ out)
{
    __shared__ float s_buf[KC * DCB];   // 32 KB overlay: red [w][c][t] -> cb [k][c]
    __shared__ float s_ze[DCB * TC];    // 4 KB  [c][t] reduced ze
    __shared__ float s_cb2[KC];         // 4 KB
    __shared__ float s_sd[16][TC];      // 8 KB
    __shared__ int   s_si[16][TC];      // 8 KB   total 56 KB

    const float* w_inT = ws;
    const float* w_out = ws + 4096;

    int tid  = threadIdx.x;
    int w    = tid >> 6;
    int wu   = __builtin_amdgcn_readfirstlane(w);
    int lane = tid & 63;
    int blk  = blockIdx.x;               // 0..511
    int b    = blk >> 5;
    int t0   = (blk & 31) * TC;
    int tl   = 2 * lane;

    // cb2 -> LDS at top
    if (tid < 256) {
        float4 q = ((const float4*)(ws + 8192))[tid];
        ((float4*)s_cb2)[tid] = q;
    }

    const float* zp = z + (size_t)b * DIN * TT + t0 + tl;

    // ---- in-projection over d in [wu*64, wu*64+64) (r13 verbatim) ----
    float ze0[DCB], ze1[DCB];
    #pragma unroll
    for (int c = 0; c < DCB; ++c) { ze0[c] = 0.f; ze1[c] = 0.f; }

    int d0 = wu * 64;
    for (int db = 0; db < 64; db += 8) {
        float2 v[8];
        #pragma unroll
        for (int j = 0; j < 8; ++j)
            v[j] = *(const float2*)(zp + (size_t)(d0 + db + j) * TT);
        #pragma unroll
        for (int j = 0; j < 8; ++j) {
            const float* wi = w_inT + (d0 + db + j) * DCB;  // uniform -> s_load
            #pragma unroll
            for (int c = 0; c < DCB; ++c) {
                ze0[c] = fmaf(wi[c], v[j].x, ze0[c]);
                ze1[c] = fmaf(wi[c], v[j].y, ze1[c]);
            }
        }
    }

    // ---- write red partials [w][c][t] ----
    {
        float* redw = s_buf + w * (DCB * TC);
        #pragma unroll
        for (int c = 0; c < DCB; ++c)
            *(float2*)(redw + c * TC + tl) = make_float2(ze0[c], ze1[c]);
    }

    // ---- prefetch cb into regs (returns during reduce) ----
    float4 p0 = ((const float4*)cb)[tid];
    float4 p1 = ((const float4*)cb)[512 + tid];
    float4 p2 = ((const float4*)cb)[1024 + tid];
    float4 p3 = ((const float4*)cb)[1536 + tid];

    __syncthreads();   // (1) red visible

    // ---- distributed reduce: this thread owns (c=w, t=tl..tl+1) ----
    {
        float sa = 0.f, sb = 0.f;
        #pragma unroll
        for (int w2 = 0; w2 < NW; ++w2) {
            float2 r = *(const float2*)(s_buf + w2 * (DCB * TC) + w * TC + tl);
            sa += r.x; sb += r.y;
        }
        float bias = in_b[w];              // uniform -> s_load
        *(float2*)(s_ze + w * TC + tl) = make_float2(sa + bias, sb + bias);
    }
    __syncthreads();   // (2) red reads done -> s_buf reusable

    // ---- overwrite s_buf with codebook ----
    ((float4*)s_buf)[tid]        = p0;
    ((float4*)s_buf)[512 + tid]  = p1;
    ((float4*)s_buf)[1024 + tid] = p2;
    ((float4*)s_buf)[1536 + tid] = p3;
    __syncthreads();   // (3) cb + s_ze visible

    // ---- scan: lane -> 4 t's (2 packed t-pairs), 64-k slice ----
    {
        int h  = lane >> 5;
        int t4 = 4 * (lane & 31);
        int s  = 2 * w + h;                // slice index, k ascending with s
        int k0 = 64 * s;

        // ze packed over t-pairs: zp2[c][p] = {ze[t4+2p], ze[t4+2p+1]}
        v2f zp2[DCB][2];
        float zr[DCB][4];
        #pragma unroll
        for (int c = 0; c < DCB; ++c) {
            float4 v = *(const float4*)(s_ze + c * TC + t4);
            zr[c][0] = v.x; zr[c][1] = v.y; zr[c][2] = v.z; zr[c][3] = v.w;
            zp2[c][0] = (v2f){v.x, v.y};
            zp2[c][1] = (v2f){v.z, v.w};
        }
        float enc2[4];
        #pragma unroll
        for (int j = 0; j < 4; ++j) {
            float e = 0.f;
            #pragma unroll
            for (int c = 0; c < DCB; ++c) e += zr[c][j] * zr[c][j];
            enc2[j] = e;
        }
        v2f enc2p[2] = { (v2f){enc2[0], enc2[1]}, (v2f){enc2[2], enc2[3]} };
        v2f neg2 = (v2f){-2.0f, -2.0f};

        float best[4] = {3.4e38f, 3.4e38f, 3.4e38f, 3.4e38f};
        int   bi[4]   = {0, 0, 0, 0};

        #pragma unroll 2
        for (int kk = 0; kk < 64; kk += 2) {
            v2f c2q = *(const v2f*)(s_cb2 + k0 + kk);   // cb2 for k, k+1
            #pragma unroll
            for (int u = 0; u < 2; ++u) {
                int k = k0 + kk + u;
                float4 r0 = ((const float4*)s_buf)[2 * k];
                float4 r1 = ((const float4*)s_buf)[2 * k + 1];
                v2f cbA = (v2f){r0.x, r0.y};
                v2f cbB = (v2f){r0.z, r0.w};
                v2f cbC = (v2f){r1.x, r1.y};
                v2f cbD = (v2f){r1.z, r1.w};
                #pragma unroll
                for (int p = 0; p < 2; ++p) {
                    // dot chain c7 -> c0, bit-identical per t to the scalar version
                    v2f acc;
                    PK_MUL_HI(acc, zp2[7][p], cbD);
                    PK_FMA_LO(acc, zp2[6][p], cbD, acc);
                    PK_FMA_HI(acc, zp2[5][p], cbC, acc);
                    PK_FMA_LO(acc, zp2[4][p], cbC, acc);
                    PK_FMA_HI(acc, zp2[3][p], cbB, acc);
                    PK_FMA_LO(acc, zp2[2][p], cbB, acc);
                    PK_FMA_HI(acc, zp2[1][p], cbA, acc);
                    PK_FMA_LO(acc, zp2[0][p], cbA, acc);
                    // dk = (enc2 - 2*dot) + cb2[k]  (fma(-2,dot,enc2) is bit-equal)
                    v2f dk2;
                    PK_FMA(dk2, acc, neg2, enc2p[p]);
                    if (u == 0) { PK_ADD_LO(dk2, dk2, c2q); }
                    else        { PK_ADD_HI(dk2, dk2, c2q); }
                    float dkx = dk2.x, dky = dk2.y;
                    if (dkx < best[2*p])     { best[2*p]     = dkx; bi[2*p]     = k; }
                    if (dky < best[2*p + 1]) { best[2*p + 1] = dky; bi[2*p + 1] = k; }
                }
            }
        }
        *(float4*)(&s_sd[s][t4]) = make_float4(best[0], best[1], best[2], best[3]);
        *(int4*)  (&s_si[s][t4]) = make_int4(bi[0], bi[1], bi[2], bi[3]);
    }
    __syncthreads();   // (4) sd/si visible

    // ---- ordered combine over 16 slices (strict <, k-ascending) ----
    float g0 = s_sd[0][tl], g1 = s_sd[0][tl + 1];
    int  gi0 = s_si[0][tl], gi1 = s_si[0][tl + 1];
    #pragma unroll
    for (int s2 = 1; s2 < 16; ++s2) {
        float d0_ = s_sd[s2][tl],  d1_ = s_sd[s2][tl + 1];
        int   i0_ = s_si[s2][tl],  i1_ = s_si[s2][tl + 1];
        if (d0_ < g0) { g0 = d0_; gi0 = i0_; }
        if (d1_ < g1) { g1 = d1_; gi1 = i1_; }
    }

    // ---- z_q rows from LDS ----
    float4 q0a = ((const float4*)s_buf)[2 * gi0], q0b = ((const float4*)s_buf)[2 * gi0 + 1];
    float4 q1a = ((const float4*)s_buf)[2 * gi1], q1b = ((const float4*)s_buf)[2 * gi1 + 1];

    // ---- commit loss + indices: wave 0 ONLY ----
    if (wu == 0) {
        float zeA[DCB], zeB[DCB];
        #pragma unroll
        for (int c = 0; c < DCB; ++c) {
            float2 zz = *(const float2*)(s_ze + c * TC + tl);
            zeA[c] = zz.x; zeB[c] = zz.y;
        }
        float cl = 0.f, f;
        f = zeA[0]-q0a.x; cl = fmaf(f,f,cl);  f = zeB[0]-q1a.x; cl = fmaf(f,f,cl);
        f = zeA[1]-q0a.y; cl = fmaf(f,f,cl);  f = zeB[1]-q1a.y; cl = fmaf(f,f,cl);
        f = zeA[2]-q0a.z; cl = fmaf(f,f,cl);  f = zeB[2]-q1a.z; cl = fmaf(f,f,cl);
        f = zeA[3]-q0a.w; cl = fmaf(f,f,cl);  f = zeB[3]-q1a.w; cl = fmaf(f,f,cl);
        f = zeA[4]-q0b.x; cl = fmaf(f,f,cl);  f = zeB[4]-q1b.x; cl = fmaf(f,f,cl);
        f = zeA[5]-q0b.y; cl = fmaf(f,f,cl);  f = zeB[5]-q1b.y; cl = fmaf(f,f,cl);
        f = zeA[6]-q0b.z; cl = fmaf(f,f,cl);  f = zeB[6]-q1b.z; cl = fmaf(f,f,cl);
        f = zeA[7]-q0b.w; cl = fmaf(f,f,cl);  f = zeB[7]-q1b.w; cl = fmaf(f,f,cl);
        #pragma unroll
        for (int off = 32; off > 0; off >>= 1) cl += __shfl_xor(cl, off, 64);
        if (lane == 0) ws_commit[blk] = cl;
        float2 iv = make_float2((float)gi0, (float)gi1);
        *(float2*)(out + (size_t)NB * DIN * TT + NB + (size_t)b * TT + t0 + tl) = iv;
    }

    // ---- out-projection over o in [wu*64, wu*64+64) (r13 verbatim) ----
    float* outp = out + (size_t)b * DIN * TT + t0 + tl;
    int o0 = wu * 64;
    #pragma unroll 4
    for (int oo = 0; oo < 64; ++oo) {
        int o = o0 + oo;
        const float* wo = w_out + o * DCB;   // uniform -> s_load_dwordx8
        float obias = out_b[o];              // uniform -> s_load
        float a0 = fmaf(wo[0], q0a.x, fmaf(wo[1], q0a.y, fmaf(wo[2], q0a.z, fmaf(wo[3], q0a.w,
                   fmaf(wo[4], q0b.x, fmaf(wo[5], q0b.y, fmaf(wo[6], q0b.z, wo[7] * q0b.w)))))));
        float a1 = fmaf(wo[0], q1a.x, fmaf(wo[1], q1a.y, fmaf(wo[2], q1a.z, fmaf(wo[3], q1a.w,
                   fmaf(wo[4], q1b.x, fmaf(wo[5], q1b.y, fmaf(wo[6], q1b.z, wo[7] * q1b.w)))))));
        *(float2*)(outp + (size_t)o * TT) = make_float2(a0 + obias, a1 + obias);
    }
}

__global__ __launch_bounds__(64) void vq_commit(
    const float* __restrict__ ws_commit, float* __restrict__ out)
{
    int b    = blockIdx.x;
    int lane = threadIdx.x;
    float s = (lane < 32) ? ws_commit[b * 32 + lane] : 0.f;
    #pragma unroll
    for (int off = 32; off > 0; off >>= 1) s += __shfl_xor(s, off, 64);
    if (lane == 0)
        out[(size_t)NB * DIN * TT + b] = s * (1.0f / (DCB * TT));
}

extern "C" void kernel_launch(void* const* d_in, const int* in_sizes, int n_in,
                              void* d_out, int out_size, void* d_ws, size_t ws_size,
                              hipStream_t stream) {
    const float* z     = (const float*)d_in[0];
    const float* in_v  = (const float*)d_in[1];
    const float* in_g  = (const float*)d_in[2];
    const float* in_b  = (const float*)d_in[3];
    const float* out_v = (const float*)d_in[4];
    const float* out_g = (const float*)d_in[5];
    const float* out_b = (const float*)d_in[6];
    const float* cb    = (const float*)d_in[7];

    float* ws  = (float*)d_ws;
    float* out = (float*)d_out;

    vq_setup<<<1, 512, 0, stream>>>(in_v, in_g, out_v, out_g, cb, ws);
    vq_main<<<512, 512, 0, stream>>>(z, in_b, out_b, cb, ws, ws + 9216, out);
    vq_commit<<<NB, 64, 0, stream>>>(ws + 9216, out);
}